// Round 9
// baseline (781.388 us; speedup 1.0000x reference)
//
#include <hip/hip_runtime.h>

#define SEQL 130
#define LSEQ 131
#define DIMM 512
#define NHEADS 8
#define MF 256
#define VSZ 523
#define NROWS (16*SEQL)          // 2080
#define NBH (16*NHEADS)          // 128
#define NBHL (NBH*SEQL)          // 16640
#define QSEG 1064960             // us elements per q/k/v segment
#define WLAYER 3145728           // us elements of weights per layer

typedef __attribute__((ext_vector_type(8))) short short8;
typedef __attribute__((ext_vector_type(8))) unsigned short us8;
typedef __attribute__((ext_vector_type(4))) unsigned short us4;
typedef __attribute__((ext_vector_type(4))) float f32x4;

__device__ __forceinline__ unsigned short f2bf(float f){
  unsigned int u = __float_as_uint(f);
  u += 0x7fffu + ((u>>16)&1u);
  return (unsigned short)(u>>16);
}
__device__ __forceinline__ float bf2f(unsigned short h){
  return __uint_as_float(((unsigned int)h)<<16);
}
__device__ __forceinline__ float gelu_f(float x){
  float x3 = x*x*x;
  return 0.5f*x*(1.f+tanhf(0.7978845608028654f*(x+0.044715f*x3)));
}
__device__ __forceinline__ unsigned enc_max(float f){
  unsigned u = __float_as_uint(f);
  return (u & 0x80000000u) ? ~u : (u | 0x80000000u);
}
__device__ __forceinline__ float dec_max(unsigned k){
  unsigned u = (k>>31) ? (k & 0x7fffffffu) : ~k;
  return __uint_as_float(u);
}
// async global->LDS, 16B per lane; lds must be wave-uniform, 16B aligned
__device__ __forceinline__ void gload16(const void* g, void* lds){
  __builtin_amdgcn_global_load_lds(
      (const __attribute__((address_space(1))) void*)g,
      (__attribute__((address_space(3))) void*)lds, 16, 0, 0);
}
__device__ __forceinline__ float blk_sum(float v){
  #pragma unroll
  for(int off=32;off;off>>=1) v += __shfl_xor(v,off);
  __shared__ float tmp_s[4];
  int t=threadIdx.x;
  if((t&63)==0) tmp_s[t>>6]=v;
  __syncthreads();
  v = tmp_s[0]+tmp_s[1]+tmp_s[2]+tmp_s[3];
  __syncthreads();
  return v;
}
__device__ __forceinline__ float blk_max(float v){
  #pragma unroll
  for(int off=32;off;off>>=1) v = fmaxf(v,__shfl_xor(v,off));
  __shared__ float tmp_m[4];
  int t=threadIdx.x;
  if((t&63)==0) tmp_m[t>>6]=v;
  __syncthreads();
  v = fmaxf(fmaxf(tmp_m[0],tmp_m[1]),fmaxf(tmp_m[2],tmp_m[3]));
  __syncthreads();
  return v;
}
__device__ __forceinline__ int tok_at(const int* __restrict__ iarr,
    const int* __restrict__ inds, int b, int p){
  if(p<3)  return iarr[b*3+p];
  if(p<67) return inds[(16+b)*64 + (p-3)];
  return inds[b*64 + (p-67)];
}

// ---------------- conv1: (32,1,16,16,16) -> relu (32,32,8,8,8), stride2 pad1
__global__ __launch_bounds__(256) void conv1_k(const float* __restrict__ x,
    const float* __restrict__ xn, const float* __restrict__ w,
    const float* __restrict__ bias, float* __restrict__ out){
  int idx = blockIdx.x*256 + threadIdx.x;
  if(idx >= 32*32*8*8*8) return;
  int ow = idx & 7, oh = (idx>>3)&7, od = (idx>>6)&7, oc = (idx>>9)&31, n = idx>>14;
  const float* xp = (n<16) ? (x + n*4096) : (xn + (n-16)*4096);
  const float* wp = w + oc*64;
  float acc = bias[oc];
  #pragma unroll
  for(int kd=0;kd<4;kd++){ int id = od*2-1+kd; if((unsigned)id>=16u) continue;
    #pragma unroll
    for(int kh=0;kh<4;kh++){ int ih = oh*2-1+kh; if((unsigned)ih>=16u) continue;
      #pragma unroll
      for(int kw=0;kw<4;kw++){ int iw = ow*2-1+kw; if((unsigned)iw>=16u) continue;
        acc += xp[(id*16+ih)*16+iw]*wp[(kd*4+kh)*4+kw];
      }}}
  out[idx] = fmaxf(acc,0.f);
}

// ---------------- conv2 im2col: c1 (32,32,8,8,8) -> icol[2048][2048] bf16 ---
__global__ __launch_bounds__(256) void im2col_k(const float* __restrict__ c1,
    unsigned short* __restrict__ icol){
  int tid = blockIdx.x*256 + threadIdx.x;
  size_t e0 = (size_t)tid*8;
  int r = (int)(e0 >> 11);
  int k0 = (int)(e0 & 2047);
  int n = r>>6, od = (r>>4)&3, oh = (r>>2)&3, ow = r&3;
  int ic = k0>>6, kd = (k0>>4)&3, kh0 = (k0>>2)&3;
  int id = od*2 - 1 + kd;
  us8 u = {};
  if((unsigned)id < 8u){
    const float* base = c1 + (size_t)(n*32+ic)*512 + id*64;
    #pragma unroll
    for(int j=0;j<8;j++){
      int kh = kh0 + (j>>2), kw = j&3;
      int ih = oh*2 - 1 + kh, iw = ow*2 - 1 + kw;
      float v = 0.f;
      if((unsigned)ih < 8u && (unsigned)iw < 8u) v = base[ih*8 + iw];
      u[j] = f2bf(v);
    }
  }
  *(us8*)(icol + e0) = u;
}

// ---------------- VQ argmin (z[row][64] f32, contiguous rows) ---------------
__global__ __launch_bounds__(256) void vq_k(const float* __restrict__ z,
    const float* __restrict__ cb, int* __restrict__ inds){
  int nf = blockIdx.x;
  __shared__ float zs[64];
  int t = threadIdx.x;
  if(t<64) zs[t] = z[(size_t)nf*64 + t];
  __syncthreads();
  float best = 3.0e38f; int bi = 0;
  for(int j=t; j<512; j+=256){
    const float* cr = cb + j*64;
    float dot=0.f, nn=0.f;
    #pragma unroll 8
    for(int d=0;d<64;d++){ float cv=cr[d]; dot += zs[d]*cv; nn += cv*cv; }
    float dist = nn - 2.f*dot;
    if(dist < best){ best=dist; bi=j; }
  }
  #pragma unroll
  for(int off=32;off;off>>=1){
    float ob = __shfl_down(best,off); int oi = __shfl_down(bi,off);
    if(ob<best || (ob==best && oi<bi)){ best=ob; bi=oi; }
  }
  __shared__ float rb[4]; __shared__ int ri[4];
  if((t&63)==0){ rb[t>>6]=best; ri[t>>6]=bi; }
  __syncthreads();
  if(t==0){
    for(int wv=1;wv<4;wv++){ if(rb[wv]<best || (rb[wv]==best && ri[wv]<bi)){ best=rb[wv]; bi=ri[wv]; } }
    inds[nf]=bi;
  }
}

__global__ __launch_bounds__(256) void embed_k(const int* __restrict__ iarr,
    const int* __restrict__ inds, const float* __restrict__ tok,
    const float* __restrict__ pos, float* __restrict__ h){
  int idx = blockIdx.x*256 + threadIdx.x;
  int c = idx & 511; int row = idx >> 9;
  int b = row/SEQL, l = row - b*SEQL;
  int tk = tok_at(iarr, inds, b, l);
  h[idx] = tok[tk*DIMM + c] + pos[l*DIMM + c];
}

// ---------------- layernorm: wave-per-row, 4 rows/block, no barriers --------
__global__ __launch_bounds__(256) void ln_k(const float* __restrict__ in,
    const float* __restrict__ g, const float* __restrict__ bb,
    unsigned short* __restrict__ out){
  int w = threadIdx.x>>6, l = threadIdx.x&63;
  int row = blockIdx.x*4 + w;
  const float* xr = in + (size_t)row*DIMM + l*8;
  f32x4 v0 = *(const f32x4*)xr;
  f32x4 v1 = *(const f32x4*)(xr+4);
  float s = v0[0]+v0[1]+v0[2]+v0[3]+v1[0]+v1[1]+v1[2]+v1[3];
  float ss = v0[0]*v0[0]+v0[1]*v0[1]+v0[2]*v0[2]+v0[3]*v0[3]
           + v1[0]*v1[0]+v1[1]*v1[1]+v1[2]*v1[2]+v1[3]*v1[3];
  #pragma unroll
  for(int off=32;off;off>>=1){ s += __shfl_xor(s,off); ss += __shfl_xor(ss,off); }
  float mu = s*(1.f/512.f);
  float var = ss*(1.f/512.f) - mu*mu;
  float inv = rsqrtf(var + 1e-5f);
  const float* gp = g + l*8; const float* bp = bb + l*8;
  us8 u;
  #pragma unroll
  for(int j=0;j<4;j++){
    u[j]   = f2bf((v0[j]-mu)*inv*gp[j]   + bp[j]);
    u[4+j] = f2bf((v1[j]-mu)*inv*gp[4+j] + bp[4+j]);
  }
  *(us8*)(out + (size_t)row*DIMM + l*8) = u;
}

// ---------------- unified prep: weights transpose/cvt + misc cvt ------------
// bid [0,18432): per-layer weight transpose (wqkv/wo/ff1/ff2)
// [18432,18496): conv2_w cvt; [18496,18544): proj cvt; [18544,18816): logit wconv
__global__ __launch_bounds__(256) void prep_k(const float* __restrict__ wq,
    const float* __restrict__ wk, const float* __restrict__ wv,
    const float* __restrict__ wo, const float* __restrict__ ff1,
    const float* __restrict__ ff2, unsigned short* __restrict__ wall,
    const float* __restrict__ conv2_w, unsigned short* __restrict__ cw2b,
    const float* __restrict__ proj, unsigned short* __restrict__ projb,
    const float* __restrict__ logits_w, unsigned short* __restrict__ logt,
    unsigned int* __restrict__ gmaxbits){
  int bid0 = blockIdx.x;
  int t = threadIdx.x;
  if(bid0==0 && t<8) gmaxbits[t] = 0u;
  if(bid0 < 18432){
    int lyr = bid0 / 3072;
    int bid = bid0 - lyr*3072;
    unsigned short* wl = wall + (size_t)lyr*WLAYER;
    const float* src; unsigned short* dst;
    int n0, k0, srcN, dstK;
    if(bid < 768){
      int nt = bid % 48, kt = bid / 48;
      n0 = nt*32; k0 = kt*32;
      int seg = n0 >> 9;
      src = (seg==0 ? wq : seg==1 ? wk : wv) + (size_t)lyr*262144;
      dst = wl; srcN = 512; dstK = 512;
    } else if(bid < 1024){
      int b2 = bid-768; int nt = b2 % 16, kt = b2 / 16;
      n0 = nt*32; k0 = kt*32; src = wo + (size_t)lyr*262144;
      dst = wl + 786432; srcN = 512; dstK = 512;
    } else if(bid < 2048){
      int b2 = bid-1024; int nt = b2 % 64, kt = b2 / 64;
      n0 = nt*32; k0 = kt*32; src = ff1 + (size_t)lyr*1048576;
      dst = wl + 1048576; srcN = 2048; dstK = 512;
    } else {
      int b2 = bid-2048; int nt = b2 % 16, kt = b2 / 16;
      n0 = nt*32; k0 = kt*32; src = ff2 + (size_t)lyr*1048576;
      dst = wl + 2097152; srcN = 512; dstK = 2048;
    }
    int srcCol0 = (bid < 768) ? (n0 & 0x1ff) : n0;
    __shared__ float tile[32][33];
    int c = t&31, r = t>>5;
    #pragma unroll
    for(int j=0;j<4;j++)
      tile[r+8*j][c] = src[(size_t)(k0+r+8*j)*srcN + srcCol0 + c];
    __syncthreads();
    #pragma unroll
    for(int j=0;j<4;j++){
      int n = n0 + r + 8*j;
      dst[(size_t)n*dstK + k0 + c] = f2bf(tile[c][r+8*j]);
    }
    return;
  }
  if(bid0 < 18544){
    const float* src; unsigned short* dst; int i;
    if(bid0 < 18496){ i = (bid0-18432)*256 + t; src = conv2_w; dst = cw2b; }
    else            { i = (bid0-18496)*256 + t; src = proj;    dst = projb; }
    const float* s = src + (size_t)i*8;
    us8 u;
    #pragma unroll
    for(int j=0;j<8;j++) u[j] = f2bf(s[j]);
    *(us8*)(dst + (size_t)i*8) = u;
    return;
  }
  {
    int b2 = bid0 - 18544;          // 272 blocks: 17 nt x 16 kt
    int nt = b2 % 17, kt = b2 / 17;
    int n0 = nt*32, k0 = kt*32;
    __shared__ float tile[32][33];
    int c = t&31, r = t>>5;
    #pragma unroll
    for(int j=0;j<4;j++){
      int n = n0+c;
      tile[r+8*j][c] = (n<VSZ) ? logits_w[(size_t)(k0+r+8*j)*VSZ + n] : 0.f;
    }
    __syncthreads();
    #pragma unroll
    for(int j=0;j<4;j++){
      int n = n0 + r + 8*j;
      if(n<VSZ) logt[(size_t)n*512 + k0 + c] = f2bf(tile[c][r+8*j]);
    }
  }
}

// ---------------- MFMA GEMM 64x128, gload_lds dbuf --------------------------
// MODE 1: bf16 qkv head-major; MODE 4: bf16 out bias+gelu
template<int MODE>
__global__ __launch_bounds__(256) void gemm64x128_k(const unsigned short* __restrict__ A,
    const unsigned short* __restrict__ Bt, const float* __restrict__ bias,
    unsigned short* __restrict__ Cb, int M, int N, int K){
  __shared__ __attribute__((aligned(16))) unsigned short As[2][4096];
  __shared__ __attribute__((aligned(16))) unsigned short Bs[2][8192];
  int t = threadIdx.x, w = t>>6, l = t&63;
  const int m0 = blockIdx.y*64, n0 = blockIdx.x*128;
  int wr = w>>1, wc = w&1;
  f32x4 acc[2][4] = {};
  auto stage = [&](unsigned short* Ad, unsigned short* Bd, int k0){
    #pragma unroll
    for(int i=0;i<2;i++){
      int c = w*2 + i;
      int r = c*8 + (l>>3);
      int gc = k0 + (((l&7) ^ (r&7))<<3);
      int ar = m0 + r; if(ar >= M) ar = 0;
      gload16(A + (size_t)ar*K + gc, Ad + c*512);
    }
    #pragma unroll
    for(int i=0;i<4;i++){
      int c = w*4 + i;
      int r = c*8 + (l>>3);
      int gc = k0 + (((l&7) ^ (r&7))<<3);
      gload16(Bt + (size_t)(n0+r)*K + gc, Bd + c*512);
    }
  };
  stage(As[0], Bs[0], 0);
  int NTk = K>>6, buf = 0;
  for(int kt=0; kt<NTk; kt++){
    __syncthreads();
    if(kt+1 < NTk) stage(As[buf^1], Bs[buf^1], (kt+1)*64);
    const unsigned short* Ab = &As[buf][0];
    const unsigned short* Bb = &Bs[buf][0];
    #pragma unroll
    for(int kk=0;kk<2;kk++){
      short8 af[2], bf[4];
      #pragma unroll
      for(int m=0;m<2;m++){
        int row = wr*32 + m*16 + (l&15);
        int slot = kk*4 + (l>>4);
        af[m] = *(const short8*)(Ab + row*64 + ((slot^(row&7))<<3));
      }
      #pragma unroll
      for(int n=0;n<4;n++){
        int col = wc*64 + n*16 + (l&15);
        int slot = kk*4 + (l>>4);
        bf[n] = *(const short8*)(Bb + col*64 + ((slot^(col&7))<<3));
      }
      #pragma unroll
      for(int m=0;m<2;m++)
        #pragma unroll
        for(int n=0;n<4;n++)
          acc[m][n] = __builtin_amdgcn_mfma_f32_16x16x32_bf16(af[m], bf[n], acc[m][n], 0, 0, 0);
    }
    buf ^= 1;
  }
  #pragma unroll
  for(int m=0;m<2;m++){
    #pragma unroll
    for(int n=0;n<4;n++){
      int col = n0 + wc*64 + n*16 + (l&15);
      #pragma unroll
      for(int i=0;i<4;i++){
        int row = m0 + wr*32 + m*16 + (l>>4)*4 + i;
        if(row < M){
          float v = acc[m][n][i];
          if(MODE==1){
            v *= (col < 1024) ? 0.35355339059327378f : 1.0f;
            int seg = col>>9, d0 = col&511;
            int hh = d0>>6, d = d0&63;
            int bb = row/SEQL, ll = row - bb*SEQL;
            Cb[(size_t)seg*QSEG + (((size_t)(bb*NHEADS+hh))*SEQL + ll)*64 + d] = f2bf(v);
          } else {
            v += bias[col];
            v = gelu_f(v);
            Cb[(size_t)row*N+col] = f2bf(v);
          }
        }
      }
    }
  }
}

// ---------------- MFMA GEMM 64x64, gload_lds dbuf ---------------------------
// MODE 0: f32 out + bias (logits); MODE 3: f32 += bias (ff2)
template<int MODE>
__global__ __launch_bounds__(256) void mgemm_k(const unsigned short* __restrict__ A,
    const unsigned short* __restrict__ Bt, const float* __restrict__ bias,
    float* __restrict__ Cf, int M, int N, int K){
  __shared__ __attribute__((aligned(16))) unsigned short As[2][4096];
  __shared__ __attribute__((aligned(16))) unsigned short Bs[2][4096];
  int t = threadIdx.x;
  const int m0 = blockIdx.y*64, n0 = blockIdx.x*64;
  int w = t>>6, l = t&63;
  int wr = w>>1, wc = w&1;
  f32x4 acc[2][2] = {};
  auto stage = [&](unsigned short* Ad, unsigned short* Bd, int k0){
    #pragma unroll
    for(int i=0;i<2;i++){
      int c = w*2 + i;
      int r = c*8 + (l>>3);
      int gc = k0 + (((l&7) ^ (r&7))<<3);
      int ar = m0 + r; if(ar >= M) ar = 0;
      gload16(A + (size_t)ar*K + gc, Ad + c*512);
      int br = n0 + r; if(br >= N) br = 0;
      gload16(Bt + (size_t)br*K + gc, Bd + c*512);
    }
  };
  stage(As[0], Bs[0], 0);
  int NT = K>>6;
  int buf = 0;
  for(int kt=0; kt<NT; kt++){
    __syncthreads();
    if(kt+1 < NT) stage(As[buf^1], Bs[buf^1], (kt+1)*64);
    const unsigned short* Ab = &As[buf][0];
    const unsigned short* Bb = &Bs[buf][0];
    #pragma unroll
    for(int kk=0;kk<2;kk++){
      short8 af[2], bf[2];
      #pragma unroll
      for(int m=0;m<2;m++){
        int row = wr*32 + m*16 + (l&15);
        int slot = kk*4 + (l>>4);
        af[m] = *(const short8*)(Ab + row*64 + ((slot^(row&7))<<3));
      }
      #pragma unroll
      for(int n=0;n<2;n++){
        int col = wc*32 + n*16 + (l&15);
        int slot = kk*4 + (l>>4);
        bf[n] = *(const short8*)(Bb + col*64 + ((slot^(col&7))<<3));
      }
      #pragma unroll
      for(int m=0;m<2;m++)
        #pragma unroll
        for(int n=0;n<2;n++)
          acc[m][n] = __builtin_amdgcn_mfma_f32_16x16x32_bf16(af[m], bf[n], acc[m][n], 0, 0, 0);
    }
    buf ^= 1;
  }
  #pragma unroll
  for(int m=0;m<2;m++){
    #pragma unroll
    for(int n=0;n<2;n++){
      int col = n0 + wc*32 + n*16 + (l&15);
      #pragma unroll
      for(int i=0;i<4;i++){
        int row = m0 + wr*32 + m*16 + (l>>4)*4 + i;
        if(row < M && col < N){
          if(MODE==3) Cf[(size_t)row*N+col] += acc[m][n][i] + bias[col];
          else        Cf[(size_t)row*N+col]  = acc[m][n][i] + bias[col];
        }
      }
    }
  }
}

// ---------------- MFMA GEMM 32x64 (M%32==0, N%64==0, K%64==0) ---------------
template<int ACC>
__global__ __launch_bounds__(256) void mgemm32_k(const unsigned short* __restrict__ A,
    const unsigned short* __restrict__ Bt, const float* __restrict__ bias,
    float* __restrict__ Cf, int N, int K){
  __shared__ __attribute__((aligned(16))) unsigned short As[2][2048];
  __shared__ __attribute__((aligned(16))) unsigned short Bs[2][4096];
  int t = threadIdx.x;
  const int m0 = blockIdx.y*32, n0 = blockIdx.x*64;
  int w = t>>6, l = t&63;
  int wm = w&1, wn2 = w>>1;
  f32x4 acc[2] = {};
  auto stage = [&](unsigned short* Ad, unsigned short* Bd, int k0){
    {
      int c = w;
      int r = c*8 + (l>>3);
      int gc = k0 + (((l&7) ^ (r&7))<<3);
      gload16(A + (size_t)(m0+r)*K + gc, Ad + c*512);
    }
    #pragma unroll
    for(int i=0;i<2;i++){
      int c = w*2 + i;
      int r = c*8 + (l>>3);
      int gc = k0 + (((l&7) ^ (r&7))<<3);
      gload16(Bt + (size_t)(n0+r)*K + gc, Bd + c*512);
    }
  };
  stage(As[0], Bs[0], 0);
  int NT = K>>6;
  int buf = 0;
  for(int kt=0; kt<NT; kt++){
    __syncthreads();
    if(kt+1 < NT) stage(As[buf^1], Bs[buf^1], (kt+1)*64);
    const unsigned short* Ab = &As[buf][0];
    const unsigned short* Bb = &Bs[buf][0];
    #pragma unroll
    for(int kk=0;kk<2;kk++){
      int arow = wm*16 + (l&15);
      int slot = kk*4 + (l>>4);
      short8 af = *(const short8*)(Ab + arow*64 + ((slot^(arow&7))<<3));
      #pragma unroll
      for(int n=0;n<2;n++){
        int col = (wn2*2+n)*16 + (l&15);
        short8 bf = *(const short8*)(Bb + col*64 + ((slot^(col&7))<<3));
        acc[n] = __builtin_amdgcn_mfma_f32_16x16x32_bf16(af, bf, acc[n], 0, 0, 0);
      }
    }
    buf ^= 1;
  }
  #pragma unroll
  for(int n=0;n<2;n++){
    int col = n0 + (wn2*2+n)*16 + (l&15);
    float bv = bias[col];
    #pragma unroll
    for(int i=0;i<4;i++){
      int row = m0 + wm*16 + (l>>4)*4 + i;
      if(ACC) Cf[(size_t)row*N+col] += acc[n][i] + bv;
      else    Cf[(size_t)row*N+col]  = acc[n][i] + bv;
    }
  }
}

// ---------------- fused feature-map kernels ---------------------------------
__global__ __launch_bounds__(256) void featA_k(const unsigned short* __restrict__ qn,
    const unsigned short* __restrict__ kn, const unsigned short* __restrict__ projl,
    unsigned short* __restrict__ qp, unsigned int* __restrict__ gmaxbits){
  int z = blockIdx.y;
  const unsigned short* dn = z ? kn : qn;
  __shared__ __attribute__((aligned(16))) float uni[32*264];
  __shared__ __attribute__((aligned(16))) unsigned short dns[2048];
  unsigned short* ps = (unsigned short*)uni;
  int t = threadIdx.x;
  int w = t>>6, l = t&63;
  size_t R0 = (size_t)blockIdx.x*32;
  {
    int c = w; int r = c*8 + (l>>3);
    int gc = (((l&7) ^ (r&7))<<3);
    gload16(dn + (R0+r)*64 + gc, dns + c*512);
  }
  #pragma unroll
  for(int i=0;i<8;i++){
    int c = w*8 + i; int r = c*8 + (l>>3);
    int gc = (((l&7) ^ (r&7))<<3);
    gload16(projl + (size_t)r*64 + gc, ps + c*512);
  }
  __syncthreads();
  int rt = w&1, cb = (w>>1)*8;
  f32x4 acc[8] = {};
  #pragma unroll
  for(int kk=0;kk<2;kk++){
    int ar = rt*16 + (l&15);
    int slot = kk*4 + (l>>4);
    short8 a = *(const short8*)(dns + ar*64 + ((slot^(ar&7))<<3));
    #pragma unroll
    for(int ct=0;ct<8;ct++){
      int br = (cb+ct)*16 + (l&15);
      short8 b = *(const short8*)(ps + br*64 + ((slot^(br&7))<<3));
      acc[ct] = __builtin_amdgcn_mfma_f32_16x16x32_bf16(a, b, acc[ct], 0, 0, 0);
    }
  }
  __syncthreads();
  #pragma unroll
  for(int ct=0;ct<8;ct++){
    int col = (cb+ct)*16 + (l&15);
    #pragma unroll
    for(int i=0;i<4;i++){
      int row = rt*16 + (l>>4)*4 + i;
      uni[row*264 + col] = acc[ct][i];
    }
  }
  __syncthreads();
  int r = t>>3, sub = t&7;
  float* rowp = uni + r*264 + sub*32;
  f32x4 v[8];
  #pragma unroll
  for(int jj=0;jj<8;jj++) v[jj] = *(const f32x4*)(rowp + jj*4);
  float m = -3.0e38f;
  #pragma unroll
  for(int jj=0;jj<8;jj++)
    #pragma unroll
    for(int i=0;i<4;i++) m = fmaxf(m, v[jj][i]);
  m = fmaxf(m, __shfl_xor(m,1));
  m = fmaxf(m, __shfl_xor(m,2));
  m = fmaxf(m, __shfl_xor(m,4));
  if(z==0){
    us8 dvu = *(const us8*)(dns + r*64 + ((sub^(r&7))<<3));
    float s2 = 0.f;
    #pragma unroll
    for(int j=0;j<8;j++){ float xx = bf2f(dvu[j]); s2 += xx*xx; }
    s2 += __shfl_xor(s2,1); s2 += __shfl_xor(s2,2); s2 += __shfl_xor(s2,4);
    float ds = 0.5f*s2;
    unsigned short* op = qp + (R0+r)*256 + sub*32;
    #pragma unroll
    for(int jj=0;jj<8;jj++){
      us4 u4;
      #pragma unroll
      for(int i=0;i<4;i++) u4[i] = f2bf(expf(v[jj][i] - ds - m)*0.0625f + 1e-4f);
      *(us4*)(op + jj*4) = u4;
    }
  } else {
    float bm = m;
    bm = fmaxf(bm, __shfl_xor(bm,8));
    bm = fmaxf(bm, __shfl_xor(bm,16));
    bm = fmaxf(bm, __shfl_xor(bm,32));
    __shared__ float wm[4];
    if(l==0) wm[w] = bm;
    __syncthreads();
    if(t==0){
      float g = fmaxf(fmaxf(wm[0],wm[1]),fmaxf(wm[2],wm[3]));
      atomicMax(gmaxbits, enc_max(g));
    }
  }
}

__global__ __launch_bounds__(256) void featB_k(const unsigned short* __restrict__ kn,
    const unsigned short* __restrict__ projl, const unsigned int* __restrict__ gmaxbits,
    unsigned short* __restrict__ kp){
  __shared__ __attribute__((aligned(16))) float uni[32*264];
  __shared__ __attribute__((aligned(16))) unsigned short dns[2048];
  unsigned short* ps = (unsigned short*)uni;
  int t = threadIdx.x;
  int w = t>>6, l = t&63;
  size_t R0 = (size_t)blockIdx.x*32;
  {
    int c = w; int r = c*8 + (l>>3);
    int gc = (((l&7) ^ (r&7))<<3);
    gload16(kn + (R0+r)*64 + gc, dns + c*512);
  }
  #pragma unroll
  for(int i=0;i<8;i++){
    int c = w*8 + i; int r = c*8 + (l>>3);
    int gc = (((l&7) ^ (r&7))<<3);
    gload16(projl + (size_t)r*64 + gc, ps + c*512);
  }
  __syncthreads();
  int rt = w&1, cb = (w>>1)*8;
  f32x4 acc[8] = {};
  #pragma unroll
  for(int kk=0;kk<2;kk++){
    int ar = rt*16 + (l&15);
    int slot = kk*4 + (l>>4);
    short8 a = *(const short8*)(dns + ar*64 + ((slot^(ar&7))<<3));
    #pragma unroll
    for(int ct=0;ct<8;ct++){
      int br = (cb+ct)*16 + (l&15);
      short8 b = *(const short8*)(ps + br*64 + ((slot^(br&7))<<3));
      acc[ct] = __builtin_amdgcn_mfma_f32_16x16x32_bf16(a, b, acc[ct], 0, 0, 0);
    }
  }
  __syncthreads();
  #pragma unroll
  for(int ct=0;ct<8;ct++){
    int col = (cb+ct)*16 + (l&15);
    #pragma unroll
    for(int i=0;i<4;i++){
      int row = rt*16 + (l>>4)*4 + i;
      uni[row*264 + col] = acc[ct][i];
    }
  }
  __syncthreads();
  float g = dec_max(gmaxbits[0]);
  int r = t>>3, sub = t&7;
  us8 dvu = *(const us8*)(dns + r*64 + ((sub^(r&7))<<3));
  float s2 = 0.f;
  #pragma unroll
  for(int j=0;j<8;j++){ float xx = bf2f(dvu[j]); s2 += xx*xx; }
  s2 += __shfl_xor(s2,1); s2 += __shfl_xor(s2,2); s2 += __shfl_xor(s2,4);
  float ds = 0.5f*s2;
  float* rowp = uni + r*264 + sub*32;
  unsigned short* op = kp + (R0+r)*256 + sub*32;
  #pragma unroll
  for(int jj=0;jj<8;jj++){
    f32x4 v = *(const f32x4*)(rowp + jj*4);
    us4 u4;
    #pragma unroll
    for(int i=0;i<4;i++) u4[i] = f2bf(expf(v[i] - ds - g)*0.0625f + 1e-4f);
    *(us4*)(op + jj*4) = u4;
  }
}

// ---------------- quadratic causal attention: all-kt staged, 2 barriers -----
__global__ __launch_bounds__(256) void attn_k(const unsigned short* __restrict__ qp,
    const unsigned short* __restrict__ kp, const unsigned short* __restrict__ vn,
    unsigned short* __restrict__ ob){
  int qt = blockIdx.x, bh = blockIdx.y;
  int b = bh>>3, hh = bh&7;
  __shared__ __attribute__((aligned(16))) unsigned short qs[8192];
  __shared__ __attribute__((aligned(16))) unsigned short ks[5*8192];
  __shared__ __attribute__((aligned(16))) unsigned short VTs[5*2176];  // [kt][d*34+r]
  __shared__ __attribute__((aligned(16))) unsigned short Sb[5*1152];   // [kt][r*36+c]
  __shared__ float dens[2][32];
  int t = threadIdx.x;
  int w = t>>6, l = t&63;
  int qh = w>>1, nc = w&1;
  // stage q tile
  #pragma unroll
  for(int i=0;i<4;i++){
    int c = w*4 + i; int r = (c<<1) + (l>>5); int sl = l&31;
    int gc = ((sl ^ (r&7))<<3);
    int gr = qt*32 + r; if(gr >= SEQL) gr = 0;
    gload16(qp + ((size_t)bh*SEQL + gr)*256 + gc, qs + c*512);
  }
  // stage all k tiles + transposed V tiles
  for(int kt=0; kt<=qt; kt++){
    #pragma unroll
    for(int i=0;i<4;i++){
      int c = w*4 + i; int r = (c<<1) + (l>>5); int sl = l&31;
      int gc = ((sl ^ (r&7))<<3);
      int gk = kt*32 + r; if(gk >= SEQL) gk = 0;
      gload16(kp + ((size_t)bh*SEQL + gk)*256 + gc, ks + kt*8192 + c*512);
    }
    {
      int rr = t>>3, od = (t&7)*8;
      int gk = kt*32 + rr;
      us8 uv = {};
      if(gk < SEQL) uv = *(const us8*)(vn + ((size_t)bh*SEQL + gk)*64 + od);
      #pragma unroll
      for(int j=0;j<8;j++) VTs[kt*2176 + (od+j)*34 + rr] = uv[j];
    }
  }
  __syncthreads();   // everything staged
  // score phase: all kt, no barriers between
  float dreg[4] = {0.f,0.f,0.f,0.f};
  for(int kt=0; kt<=qt; kt++){
    const unsigned short* kb = ks + kt*8192;
    f32x4 sacc = {};
    #pragma unroll
    for(int kk=0;kk<8;kk++){
      int ar = qh*16 + (l&15); int slot = kk*4 + (l>>4);
      short8 a = *(const short8*)(qs + ar*256 + ((slot^(ar&7))<<3));
      int br = nc*16 + (l&15);
      short8 bb2 = *(const short8*)(kb + br*256 + ((slot^(br&7))<<3));
      sacc = __builtin_amdgcn_mfma_f32_16x16x32_bf16(a, bb2, sacc, 0, 0, 0);
    }
    int scol = nc*16 + (l&15);
    int gcol = kt*32 + scol;
    float dp[4];
    #pragma unroll
    for(int i=0;i<4;i++){
      int sr = qh*16 + (l>>4)*4 + i;
      int grw = qt*32 + sr;
      float v2 = sacc[i];
      if(gcol > grw) v2 = 0.f;
      Sb[kt*1152 + sr*36 + scol] = f2bf(v2);
      dp[i] = v2;
    }
    #pragma unroll
    for(int off=1;off<16;off<<=1)
      #pragma unroll
      for(int i=0;i<4;i++) dp[i] += __shfl_xor(dp[i], off);
    #pragma unroll
    for(int i=0;i<4;i++) dreg[i] += dp[i];
  }
  if((l&15)==0){
    #pragma unroll
    for(int i=0;i<4;i++) dens[nc][qh*16 + (l>>4)*4 + i] = dreg[i];
  }
  __syncthreads();   // Sb + dens ready
  // PV phase
  f32x4 oacc[2] = {};
  for(int kt=0; kt<=qt; kt++){
    short8 a2 = *(const short8*)(Sb + kt*1152 + (qh*16 + (l&15))*36 + (l>>4)*8);
    #pragma unroll
    for(int n2=0;n2<2;n2++){
      int d = nc*32 + n2*16 + (l&15);
      short8 b2 = *(const short8*)(VTs + kt*2176 + d*34 + (l>>4)*8);
      oacc[n2] = __builtin_amdgcn_mfma_f32_16x16x32_bf16(a2, b2, oacc[n2], 0, 0, 0);
    }
  }
  #pragma unroll
  for(int n2=0;n2<2;n2++){
    int d = nc*32 + n2*16 + (l&15);
    #pragma unroll
    for(int i=0;i<4;i++){
      int rit = qh*16 + (l>>4)*4 + i;
      int gr = qt*32 + rit;
      if(gr < SEQL){
        float inv = 1.f/(dens[0][rit] + dens[1][rit]);
        ob[((size_t)(b*SEQL+gr))*DIMM + hh*64 + d] = f2bf(oacc[n2][i]*inv);
      }
    }
  }
}

// ---------------- loss ------------------------------------------------------
__global__ __launch_bounds__(256) void loss_k(const float* __restrict__ logits,
    const int* __restrict__ iarr, const int* __restrict__ inds,
    float* __restrict__ rnll){
  int row = blockIdx.x; int t = threadIdx.x;
  const float* lr = logits + (size_t)row*VSZ;
  float m = -3.0e38f;
  for(int j=t;j<VSZ;j+=256) m = fmaxf(m, lr[j]);
  m = blk_max(m);
  float s = 0.f;
  for(int j=t;j<VSZ;j+=256) s += expf(lr[j]-m);
  s = blk_sum(s);
  if(t==0){
    int b = row/SEQL, l = row - b*SEQL;
    int tgt = tok_at(iarr, inds, b, l+1);
    rnll[row] = (m + logf(s)) - lr[tgt];
  }
}

__global__ __launch_bounds__(256) void fin_k(const float* __restrict__ rnll,
    float* __restrict__ out){
  int t = threadIdx.x;
  float s = 0.f;
  for(int i=t;i<NROWS;i+=256) s += rnll[i];
  s = blk_sum(s);
  if(t==0) out[0] = s/(float)NROWS;
}

// ---------------------------------------------------------------------------
extern "C" void kernel_launch(void* const* d_in, const int* in_sizes, int n_in,
                              void* d_out, int out_size, void* d_ws, size_t ws_size,
                              hipStream_t stream){
  (void)in_sizes; (void)n_in; (void)out_size; (void)ws_size;
  const float* x        = (const float*)d_in[0];
  const float* xn       = (const float*)d_in[1];
  const int*   iarr     = (const int*)  d_in[2];
  const float* conv1_w  = (const float*)d_in[3];
  const float* conv1_b  = (const float*)d_in[4];
  const float* conv2_w  = (const float*)d_in[5];
  const float* conv2_b  = (const float*)d_in[6];
  const float* codebook = (const float*)d_in[7];
  const float* proj     = (const float*)d_in[8];
  const float* tok_emb  = (const float*)d_in[9];
  const float* pos_emb  = (const float*)d_in[10];
  const float* ln1_g    = (const float*)d_in[11];
  const float* ln1_b    = (const float*)d_in[12];
  const float* wq       = (const float*)d_in[13];
  const float* wk       = (const float*)d_in[14];
  const float* wv       = (const float*)d_in[15];
  const float* wo       = (const float*)d_in[16];
  const float* bo       = (const float*)d_in[17];
  const float* ln2_g    = (const float*)d_in[18];
  const float* ln2_b    = (const float*)d_in[19];
  const float* ff1_w    = (const float*)d_in[20];
  const float* ff1_b    = (const float*)d_in[21];
  const float* ff2_w    = (const float*)d_in[22];
  const float* ff2_b    = (const float*)d_in[23];
  const float* lnf_g    = (const float*)d_in[24];
  const float* lnf_b    = (const float*)d_in[25];
  const float* logits_w = (const float*)d_in[26];
  const float* logits_b = (const float*)d_in[27];

  float* wsf = (float*)d_ws;
  size_t off = 0;
  unsigned short* qp_bf = (unsigned short*)(wsf + off); off += 2129920;
  unsigned short* kp_bf = (unsigned short*)(wsf + off); off += 2129920;
  float* h = wsf + off; off += 1064960;
  unsigned short* x1b = (unsigned short*)(wsf + off); off += 532480;
  unsigned short* qkvb = (unsigned short*)(wsf + off); off += 1597440;
  unsigned short* ob  = (unsigned short*)(wsf + off); off += 532480;
  unsigned short* projb = (unsigned short*)(wsf + off); off += 49152;
  unsigned short* wall  = (unsigned short*)(wsf + off); off += 9437184; // 6 layers
  unsigned short* logt  = (unsigned short*)(wsf + off); off += 133888;
  unsigned short* ffmid = (unsigned short*)(wsf + off); off += 2129920;
  float* logits = wsf + off; off += 1087840;
  int* inds = (int*)(wsf + off); off += 2048;
  unsigned int* gmaxbits = (unsigned int*)(wsf + off); off += 64;
  float* rnll = wsf + off; off += 2112;

  // pre-loop aliases into regions that are dead before the layer loop
  float* c1 = logits;                                  // 524288 f32
  unsigned short* icol = ffmid;                        // 2048*2048 us
  float* zbuf = (float*)qp_bf;                         // 2048*64 f32
  unsigned short* cw2b = (unsigned short*)kp_bf;       // 64*2048 us

  unsigned short* qnb = qkvb;
  unsigned short* knb = qkvb + QSEG;
  unsigned short* vnb = qkvb + 2*QSEG;

  prep_k<<<18816,256,0,stream>>>(wq, wk, wv, wo, ff1_w, ff2_w, wall,
      conv2_w, cw2b, proj, projb, logits_w, logt, gmaxbits);
  conv1_k<<<2048,256,0,stream>>>(x, xn, conv1_w, conv1_b, c1);
  im2col_k<<<2048,256,0,stream>>>(c1, icol);
  mgemm32_k<0><<<dim3(1,64),256,0,stream>>>(icol, cw2b, conv2_b, zbuf, 64, 2048);
  vq_k<<<2048,256,0,stream>>>(zbuf, codebook, inds);
  embed_k<<<(NROWS*DIMM)/256,256,0,stream>>>(iarr, inds, tok_emb, pos_emb, h);

  for(int l=0;l<6;l++){
    unsigned short* wl    = wall + (size_t)l*WLAYER;
    unsigned short* wqkvt = wl;
    unsigned short* wot   = wl + 786432;
    unsigned short* ff1t  = wl + 1048576;
    unsigned short* ff2t  = wl + 2097152;
    ln_k<<<520,256,0,stream>>>(h, ln1_g+l*DIMM, ln1_b+l*DIMM, x1b);
    gemm64x128_k<1><<<dim3(12,33),256,0,stream>>>(x1b, wqkvt, nullptr, qkvb, NROWS, 1536, DIMM);
    featA_k<<<dim3(520,2),256,0,stream>>>(qnb, knb, projb + l*16384, qp_bf, gmaxbits + l);
    featB_k<<<520,256,0,stream>>>(knb, projb + l*16384, gmaxbits + l, kp_bf);
    attn_k<<<dim3(5,NBH),256,0,stream>>>(qp_bf, kp_bf, vnb, ob);
    mgemm32_k<1><<<dim3(8,65),256,0,stream>>>(ob, wot, bo+l*DIMM, h, DIMM, DIMM);
    ln_k<<<520,256,0,stream>>>(h, ln2_g+l*DIMM, ln2_b+l*DIMM, x1b);
    gemm64x128_k<4><<<dim3(16,33),256,0,stream>>>(x1b, ff1t, ff1_b+l*2048, ffmid, NROWS, 2048, DIMM);
    mgemm_k<3><<<dim3(8,33),256,0,stream>>>(ffmid, ff2t, ff2_b+l*DIMM, h, NROWS, DIMM, 2048);
  }

  ln_k<<<520,256,0,stream>>>(h, lnf_g, lnf_b, x1b);
  mgemm_k<0><<<dim3(9,33),256,0,stream>>>(x1b, logt, logits_b, logits, NROWS, VSZ, DIMM);
  loss_k<<<NROWS,256,0,stream>>>(logits, iarr, inds, rnll);
  fin_k<<<1,256,0,stream>>>(rnll, (float*)d_out);
}

// Round 10
// 731.638 us; speedup vs baseline: 1.0680x; 1.0680x over previous
//
#include <hip/hip_runtime.h>

#define SEQL 130
#define LSEQ 131
#define DIMM 512
#define NHEADS 8
#define MF 256
#define VSZ 523
#define NROWS (16*SEQL)          // 2080
#define NBH (16*NHEADS)          // 128
#define NBHL (NBH*SEQL)          // 16640
#define QSEG 1064960             // us elements per q/k/v segment
#define WLAYER 3145728           // us elements of weights per layer

typedef __attribute__((ext_vector_type(8))) short short8;
typedef __attribute__((ext_vector_type(8))) unsigned short us8;
typedef __attribute__((ext_vector_type(4))) unsigned short us4;
typedef __attribute__((ext_vector_type(4))) float f32x4;

__device__ __forceinline__ unsigned short f2bf(float f){
  unsigned int u = __float_as_uint(f);
  u += 0x7fffu + ((u>>16)&1u);
  return (unsigned short)(u>>16);
}
__device__ __forceinline__ float bf2f(unsigned short h){
  return __uint_as_float(((unsigned int)h)<<16);
}
__device__ __forceinline__ float gelu_f(float x){
  float x3 = x*x*x;
  return 0.5f*x*(1.f+tanhf(0.7978845608028654f*(x+0.044715f*x3)));
}
__device__ __forceinline__ unsigned enc_max(float f){
  unsigned u = __float_as_uint(f);
  return (u & 0x80000000u) ? ~u : (u | 0x80000000u);
}
__device__ __forceinline__ float dec_max(unsigned k){
  unsigned u = (k>>31) ? (k & 0x7fffffffu) : ~k;
  return __uint_as_float(u);
}
// async global->LDS, 16B per lane; lds must be wave-uniform, 16B aligned
__device__ __forceinline__ void gload16(const void* g, void* lds){
  __builtin_amdgcn_global_load_lds(
      (const __attribute__((address_space(1))) void*)g,
      (__attribute__((address_space(3))) void*)lds, 16, 0, 0);
}
__device__ __forceinline__ float blk_sum(float v){
  #pragma unroll
  for(int off=32;off;off>>=1) v += __shfl_xor(v,off);
  __shared__ float tmp_s[4];
  int t=threadIdx.x;
  if((t&63)==0) tmp_s[t>>6]=v;
  __syncthreads();
  v = tmp_s[0]+tmp_s[1]+tmp_s[2]+tmp_s[3];
  __syncthreads();
  return v;
}
__device__ __forceinline__ float blk_max(float v){
  #pragma unroll
  for(int off=32;off;off>>=1) v = fmaxf(v,__shfl_xor(v,off));
  __shared__ float tmp_m[4];
  int t=threadIdx.x;
  if((t&63)==0) tmp_m[t>>6]=v;
  __syncthreads();
  v = fmaxf(fmaxf(tmp_m[0],tmp_m[1]),fmaxf(tmp_m[2],tmp_m[3]));
  __syncthreads();
  return v;
}
__device__ __forceinline__ int tok_at(const int* __restrict__ iarr,
    const int* __restrict__ inds, int b, int p){
  if(p<3)  return iarr[b*3+p];
  if(p<67) return inds[(16+b)*64 + (p-3)];
  return inds[b*64 + (p-67)];
}

// ---------------- conv1: (32,1,16,16,16) -> relu (32,32,8,8,8), stride2 pad1
__global__ __launch_bounds__(256) void conv1_k(const float* __restrict__ x,
    const float* __restrict__ xn, const float* __restrict__ w,
    const float* __restrict__ bias, float* __restrict__ out){
  int idx = blockIdx.x*256 + threadIdx.x;
  if(idx >= 32*32*8*8*8) return;
  int ow = idx & 7, oh = (idx>>3)&7, od = (idx>>6)&7, oc = (idx>>9)&31, n = idx>>14;
  const float* xp = (n<16) ? (x + n*4096) : (xn + (n-16)*4096);
  const float* wp = w + oc*64;
  float acc = bias[oc];
  #pragma unroll
  for(int kd=0;kd<4;kd++){ int id = od*2-1+kd; if((unsigned)id>=16u) continue;
    #pragma unroll
    for(int kh=0;kh<4;kh++){ int ih = oh*2-1+kh; if((unsigned)ih>=16u) continue;
      #pragma unroll
      for(int kw=0;kw<4;kw++){ int iw = ow*2-1+kw; if((unsigned)iw>=16u) continue;
        acc += xp[(id*16+ih)*16+iw]*wp[(kd*4+kh)*4+kw];
      }}}
  out[idx] = fmaxf(acc,0.f);
}

// ---------------- conv2 im2col: c1 (32,32,8,8,8) -> icol[2048][2048] bf16 ---
__global__ __launch_bounds__(256) void im2col_k(const float* __restrict__ c1,
    unsigned short* __restrict__ icol){
  int tid = blockIdx.x*256 + threadIdx.x;
  size_t e0 = (size_t)tid*8;
  int r = (int)(e0 >> 11);
  int k0 = (int)(e0 & 2047);
  int n = r>>6, od = (r>>4)&3, oh = (r>>2)&3, ow = r&3;
  int ic = k0>>6, kd = (k0>>4)&3, kh0 = (k0>>2)&3;
  int id = od*2 - 1 + kd;
  us8 u = {};
  if((unsigned)id < 8u){
    const float* base = c1 + (size_t)(n*32+ic)*512 + id*64;
    #pragma unroll
    for(int j=0;j<8;j++){
      int kh = kh0 + (j>>2), kw = j&3;
      int ih = oh*2 - 1 + kh, iw = ow*2 - 1 + kw;
      float v = 0.f;
      if((unsigned)ih < 8u && (unsigned)iw < 8u) v = base[ih*8 + iw];
      u[j] = f2bf(v);
    }
  }
  *(us8*)(icol + e0) = u;
}

// ---------------- VQ argmin (z[row][64] f32, contiguous rows) ---------------
__global__ __launch_bounds__(256) void vq_k(const float* __restrict__ z,
    const float* __restrict__ cb, int* __restrict__ inds){
  int nf = blockIdx.x;
  __shared__ float zs[64];
  int t = threadIdx.x;
  if(t<64) zs[t] = z[(size_t)nf*64 + t];
  __syncthreads();
  float best = 3.0e38f; int bi = 0;
  for(int j=t; j<512; j+=256){
    const float* cr = cb + j*64;
    float dot=0.f, nn=0.f;
    #pragma unroll 8
    for(int d=0;d<64;d++){ float cv=cr[d]; dot += zs[d]*cv; nn += cv*cv; }
    float dist = nn - 2.f*dot;
    if(dist < best){ best=dist; bi=j; }
  }
  #pragma unroll
  for(int off=32;off;off>>=1){
    float ob = __shfl_down(best,off); int oi = __shfl_down(bi,off);
    if(ob<best || (ob==best && oi<bi)){ best=ob; bi=oi; }
  }
  __shared__ float rb[4]; __shared__ int ri[4];
  if((t&63)==0){ rb[t>>6]=best; ri[t>>6]=bi; }
  __syncthreads();
  if(t==0){
    for(int wv=1;wv<4;wv++){ if(rb[wv]<best || (rb[wv]==best && ri[wv]<bi)){ best=rb[wv]; bi=ri[wv]; } }
    inds[nf]=bi;
  }
}

__global__ __launch_bounds__(256) void embed_k(const int* __restrict__ iarr,
    const int* __restrict__ inds, const float* __restrict__ tok,
    const float* __restrict__ pos, float* __restrict__ h){
  int idx = blockIdx.x*256 + threadIdx.x;
  int c = idx & 511; int row = idx >> 9;
  int b = row/SEQL, l = row - b*SEQL;
  int tk = tok_at(iarr, inds, b, l);
  h[idx] = tok[tk*DIMM + c] + pos[l*DIMM + c];
}

// ---------------- layernorm: wave-per-row, 4 rows/block, no barriers --------
__global__ __launch_bounds__(256) void ln_k(const float* __restrict__ in,
    const float* __restrict__ g, const float* __restrict__ bb,
    unsigned short* __restrict__ out){
  int w = threadIdx.x>>6, l = threadIdx.x&63;
  int row = blockIdx.x*4 + w;
  const float* xr = in + (size_t)row*DIMM + l*8;
  f32x4 v0 = *(const f32x4*)xr;
  f32x4 v1 = *(const f32x4*)(xr+4);
  float s = v0[0]+v0[1]+v0[2]+v0[3]+v1[0]+v1[1]+v1[2]+v1[3];
  float ss = v0[0]*v0[0]+v0[1]*v0[1]+v0[2]*v0[2]+v0[3]*v0[3]
           + v1[0]*v1[0]+v1[1]*v1[1]+v1[2]*v1[2]+v1[3]*v1[3];
  #pragma unroll
  for(int off=32;off;off>>=1){ s += __shfl_xor(s,off); ss += __shfl_xor(ss,off); }
  float mu = s*(1.f/512.f);
  float var = ss*(1.f/512.f) - mu*mu;
  float inv = rsqrtf(var + 1e-5f);
  const float* gp = g + l*8; const float* bp = bb + l*8;
  us8 u;
  #pragma unroll
  for(int j=0;j<4;j++){
    u[j]   = f2bf((v0[j]-mu)*inv*gp[j]   + bp[j]);
    u[4+j] = f2bf((v1[j]-mu)*inv*gp[4+j] + bp[4+j]);
  }
  *(us8*)(out + (size_t)row*DIMM + l*8) = u;
}

// ---------------- unified prep: weights transpose/cvt + misc cvt ------------
__global__ __launch_bounds__(256) void prep_k(const float* __restrict__ wq,
    const float* __restrict__ wk, const float* __restrict__ wv,
    const float* __restrict__ wo, const float* __restrict__ ff1,
    const float* __restrict__ ff2, unsigned short* __restrict__ wall,
    const float* __restrict__ conv2_w, unsigned short* __restrict__ cw2b,
    const float* __restrict__ proj, unsigned short* __restrict__ projb,
    const float* __restrict__ logits_w, unsigned short* __restrict__ logt,
    unsigned int* __restrict__ gmaxbits){
  int bid0 = blockIdx.x;
  int t = threadIdx.x;
  if(bid0==0 && t<8) gmaxbits[t] = 0u;
  if(bid0 < 18432){
    int lyr = bid0 / 3072;
    int bid = bid0 - lyr*3072;
    unsigned short* wl = wall + (size_t)lyr*WLAYER;
    const float* src; unsigned short* dst;
    int n0, k0, srcN, dstK;
    if(bid < 768){
      int nt = bid % 48, kt = bid / 48;
      n0 = nt*32; k0 = kt*32;
      int seg = n0 >> 9;
      src = (seg==0 ? wq : seg==1 ? wk : wv) + (size_t)lyr*262144;
      dst = wl; srcN = 512; dstK = 512;
    } else if(bid < 1024){
      int b2 = bid-768; int nt = b2 % 16, kt = b2 / 16;
      n0 = nt*32; k0 = kt*32; src = wo + (size_t)lyr*262144;
      dst = wl + 786432; srcN = 512; dstK = 512;
    } else if(bid < 2048){
      int b2 = bid-1024; int nt = b2 % 64, kt = b2 / 64;
      n0 = nt*32; k0 = kt*32; src = ff1 + (size_t)lyr*1048576;
      dst = wl + 1048576; srcN = 2048; dstK = 512;
    } else {
      int b2 = bid-2048; int nt = b2 % 16, kt = b2 / 16;
      n0 = nt*32; k0 = kt*32; src = ff2 + (size_t)lyr*1048576;
      dst = wl + 2097152; srcN = 512; dstK = 2048;
    }
    int srcCol0 = (bid < 768) ? (n0 & 0x1ff) : n0;
    __shared__ float tile[32][33];
    int c = t&31, r = t>>5;
    #pragma unroll
    for(int j=0;j<4;j++)
      tile[r+8*j][c] = src[(size_t)(k0+r+8*j)*srcN + srcCol0 + c];
    __syncthreads();
    #pragma unroll
    for(int j=0;j<4;j++){
      int n = n0 + r + 8*j;
      dst[(size_t)n*dstK + k0 + c] = f2bf(tile[c][r+8*j]);
    }
    return;
  }
  if(bid0 < 18544){
    const float* src; unsigned short* dst; int i;
    if(bid0 < 18496){ i = (bid0-18432)*256 + t; src = conv2_w; dst = cw2b; }
    else            { i = (bid0-18496)*256 + t; src = proj;    dst = projb; }
    const float* s = src + (size_t)i*8;
    us8 u;
    #pragma unroll
    for(int j=0;j<8;j++) u[j] = f2bf(s[j]);
    *(us8*)(dst + (size_t)i*8) = u;
    return;
  }
  {
    int b2 = bid0 - 18544;          // 272 blocks: 17 nt x 16 kt
    int nt = b2 % 17, kt = b2 / 17;
    int n0 = nt*32, k0 = kt*32;
    __shared__ float tile[32][33];
    int c = t&31, r = t>>5;
    #pragma unroll
    for(int j=0;j<4;j++){
      int n = n0+c;
      tile[r+8*j][c] = (n<VSZ) ? logits_w[(size_t)(k0+r+8*j)*VSZ + n] : 0.f;
    }
    __syncthreads();
    #pragma unroll
    for(int j=0;j<4;j++){
      int n = n0 + r + 8*j;
      if(n<VSZ) logt[(size_t)n*512 + k0 + c] = f2bf(tile[c][r+8*j]);
    }
  }
}

// ---------------- MFMA GEMM 64x128, gload_lds dbuf --------------------------
// MODE 1: bf16 qkv head-major; MODE 4: bf16 out bias+gelu
template<int MODE>
__global__ __launch_bounds__(256) void gemm64x128_k(const unsigned short* __restrict__ A,
    const unsigned short* __restrict__ Bt, const float* __restrict__ bias,
    unsigned short* __restrict__ Cb, int M, int N, int K){
  __shared__ __attribute__((aligned(16))) unsigned short As[2][4096];
  __shared__ __attribute__((aligned(16))) unsigned short Bs[2][8192];
  int t = threadIdx.x, w = t>>6, l = t&63;
  const int m0 = blockIdx.y*64, n0 = blockIdx.x*128;
  int wr = w>>1, wc = w&1;
  f32x4 acc[2][4] = {};
  auto stage = [&](unsigned short* Ad, unsigned short* Bd, int k0){
    #pragma unroll
    for(int i=0;i<2;i++){
      int c = w*2 + i;
      int r = c*8 + (l>>3);
      int gc = k0 + (((l&7) ^ (r&7))<<3);
      int ar = m0 + r; if(ar >= M) ar = 0;
      gload16(A + (size_t)ar*K + gc, Ad + c*512);
    }
    #pragma unroll
    for(int i=0;i<4;i++){
      int c = w*4 + i;
      int r = c*8 + (l>>3);
      int gc = k0 + (((l&7) ^ (r&7))<<3);
      gload16(Bt + (size_t)(n0+r)*K + gc, Bd + c*512);
    }
  };
  stage(As[0], Bs[0], 0);
  int NTk = K>>6, buf = 0;
  for(int kt=0; kt<NTk; kt++){
    __syncthreads();
    if(kt+1 < NTk) stage(As[buf^1], Bs[buf^1], (kt+1)*64);
    const unsigned short* Ab = &As[buf][0];
    const unsigned short* Bb = &Bs[buf][0];
    #pragma unroll
    for(int kk=0;kk<2;kk++){
      short8 af[2], bf[4];
      #pragma unroll
      for(int m=0;m<2;m++){
        int row = wr*32 + m*16 + (l&15);
        int slot = kk*4 + (l>>4);
        af[m] = *(const short8*)(Ab + row*64 + ((slot^(row&7))<<3));
      }
      #pragma unroll
      for(int n=0;n<4;n++){
        int col = wc*64 + n*16 + (l&15);
        int slot = kk*4 + (l>>4);
        bf[n] = *(const short8*)(Bb + col*64 + ((slot^(col&7))<<3));
      }
      #pragma unroll
      for(int m=0;m<2;m++)
        #pragma unroll
        for(int n=0;n<4;n++)
          acc[m][n] = __builtin_amdgcn_mfma_f32_16x16x32_bf16(af[m], bf[n], acc[m][n], 0, 0, 0);
    }
    buf ^= 1;
  }
  #pragma unroll
  for(int m=0;m<2;m++){
    #pragma unroll
    for(int n=0;n<4;n++){
      int col = n0 + wc*64 + n*16 + (l&15);
      #pragma unroll
      for(int i=0;i<4;i++){
        int row = m0 + wr*32 + m*16 + (l>>4)*4 + i;
        if(row < M){
          float v = acc[m][n][i];
          if(MODE==1){
            v *= (col < 1024) ? 0.35355339059327378f : 1.0f;
            int seg = col>>9, d0 = col&511;
            int hh = d0>>6, d = d0&63;
            int bb = row/SEQL, ll = row - bb*SEQL;
            Cb[(size_t)seg*QSEG + (((size_t)(bb*NHEADS+hh))*SEQL + ll)*64 + d] = f2bf(v);
          } else {
            v += bias[col];
            v = gelu_f(v);
            Cb[(size_t)row*N+col] = f2bf(v);
          }
        }
      }
    }
  }
}

// ---------------- MFMA GEMM 64x64, gload_lds dbuf (logits) ------------------
__global__ __launch_bounds__(256) void mgemm_k(const unsigned short* __restrict__ A,
    const unsigned short* __restrict__ Bt, const float* __restrict__ bias,
    float* __restrict__ Cf, int M, int N, int K){
  __shared__ __attribute__((aligned(16))) unsigned short As[2][4096];
  __shared__ __attribute__((aligned(16))) unsigned short Bs[2][4096];
  int t = threadIdx.x;
  const int m0 = blockIdx.y*64, n0 = blockIdx.x*64;
  int w = t>>6, l = t&63;
  int wr = w>>1, wc = w&1;
  f32x4 acc[2][2] = {};
  auto stage = [&](unsigned short* Ad, unsigned short* Bd, int k0){
    #pragma unroll
    for(int i=0;i<2;i++){
      int c = w*2 + i;
      int r = c*8 + (l>>3);
      int gc = k0 + (((l&7) ^ (r&7))<<3);
      int ar = m0 + r; if(ar >= M) ar = 0;
      gload16(A + (size_t)ar*K + gc, Ad + c*512);
      int br = n0 + r; if(br >= N) br = 0;
      gload16(Bt + (size_t)br*K + gc, Bd + c*512);
    }
  };
  stage(As[0], Bs[0], 0);
  int NT = K>>6;
  int buf = 0;
  for(int kt=0; kt<NT; kt++){
    __syncthreads();
    if(kt+1 < NT) stage(As[buf^1], Bs[buf^1], (kt+1)*64);
    const unsigned short* Ab = &As[buf][0];
    const unsigned short* Bb = &Bs[buf][0];
    #pragma unroll
    for(int kk=0;kk<2;kk++){
      short8 af[2], bf[2];
      #pragma unroll
      for(int m=0;m<2;m++){
        int row = wr*32 + m*16 + (l&15);
        int slot = kk*4 + (l>>4);
        af[m] = *(const short8*)(Ab + row*64 + ((slot^(row&7))<<3));
      }
      #pragma unroll
      for(int n=0;n<2;n++){
        int col = wc*32 + n*16 + (l&15);
        int slot = kk*4 + (l>>4);
        bf[n] = *(const short8*)(Bb + col*64 + ((slot^(col&7))<<3));
      }
      #pragma unroll
      for(int m=0;m<2;m++)
        #pragma unroll
        for(int n=0;n<2;n++)
          acc[m][n] = __builtin_amdgcn_mfma_f32_16x16x32_bf16(af[m], bf[n], acc[m][n], 0, 0, 0);
    }
    buf ^= 1;
  }
  #pragma unroll
  for(int m=0;m<2;m++){
    #pragma unroll
    for(int n=0;n<2;n++){
      int col = n0 + wc*32 + n*16 + (l&15);
      #pragma unroll
      for(int i=0;i<4;i++){
        int row = m0 + wr*32 + m*16 + (l>>4)*4 + i;
        if(row < M && col < N){
          Cf[(size_t)row*N+col] = acc[m][n][i] + bias[col];
        }
      }
    }
  }
}

// ---------------- MFMA GEMM 32x64 (M%32==0, N%64==0, K%64==0) ---------------
template<int ACC>
__global__ __launch_bounds__(256) void mgemm32_k(const unsigned short* __restrict__ A,
    const unsigned short* __restrict__ Bt, const float* __restrict__ bias,
    float* __restrict__ Cf, int N, int K){
  __shared__ __attribute__((aligned(16))) unsigned short As[2][2048];
  __shared__ __attribute__((aligned(16))) unsigned short Bs[2][4096];
  int t = threadIdx.x;
  const int m0 = blockIdx.y*32, n0 = blockIdx.x*64;
  int w = t>>6, l = t&63;
  int wm = w&1, wn2 = w>>1;
  f32x4 acc[2] = {};
  auto stage = [&](unsigned short* Ad, unsigned short* Bd, int k0){
    {
      int c = w;
      int r = c*8 + (l>>3);
      int gc = k0 + (((l&7) ^ (r&7))<<3);
      gload16(A + (size_t)(m0+r)*K + gc, Ad + c*512);
    }
    #pragma unroll
    for(int i=0;i<2;i++){
      int c = w*2 + i;
      int r = c*8 + (l>>3);
      int gc = k0 + (((l&7) ^ (r&7))<<3);
      gload16(Bt + (size_t)(n0+r)*K + gc, Bd + c*512);
    }
  };
  stage(As[0], Bs[0], 0);
  int NT = K>>6;
  int buf = 0;
  for(int kt=0; kt<NT; kt++){
    __syncthreads();
    if(kt+1 < NT) stage(As[buf^1], Bs[buf^1], (kt+1)*64);
    const unsigned short* Ab = &As[buf][0];
    const unsigned short* Bb = &Bs[buf][0];
    #pragma unroll
    for(int kk=0;kk<2;kk++){
      int arow = wm*16 + (l&15);
      int slot = kk*4 + (l>>4);
      short8 af = *(const short8*)(Ab + arow*64 + ((slot^(arow&7))<<3));
      #pragma unroll
      for(int n=0;n<2;n++){
        int col = (wn2*2+n)*16 + (l&15);
        short8 bf = *(const short8*)(Bb + col*64 + ((slot^(col&7))<<3));
        acc[n] = __builtin_amdgcn_mfma_f32_16x16x32_bf16(af, bf, acc[n], 0, 0, 0);
      }
    }
    buf ^= 1;
  }
  #pragma unroll
  for(int n=0;n<2;n++){
    int col = n0 + (wn2*2+n)*16 + (l&15);
    float bv = bias[col];
    #pragma unroll
    for(int i=0;i<4;i++){
      int row = m0 + wm*16 + (l>>4)*4 + i;
      if(ACC) Cf[(size_t)row*N+col] += acc[n][i] + bv;
      else    Cf[(size_t)row*N+col]  = acc[n][i] + bv;
    }
  }
}

// ---------------- fused feature-map kernels ---------------------------------
__global__ __launch_bounds__(256) void featA_k(const unsigned short* __restrict__ qn,
    const unsigned short* __restrict__ kn, const unsigned short* __restrict__ projl,
    unsigned short* __restrict__ qp, unsigned int* __restrict__ gmaxbits){
  int z = blockIdx.y;
  const unsigned short* dn = z ? kn : qn;
  __shared__ __attribute__((aligned(16))) float uni[32*264];
  __shared__ __attribute__((aligned(16))) unsigned short dns[2048];
  unsigned short* ps = (unsigned short*)uni;
  int t = threadIdx.x;
  int w = t>>6, l = t&63;
  size_t R0 = (size_t)blockIdx.x*32;
  {
    int c = w; int r = c*8 + (l>>3);
    int gc = (((l&7) ^ (r&7))<<3);
    gload16(dn + (R0+r)*64 + gc, dns + c*512);
  }
  #pragma unroll
  for(int i=0;i<8;i++){
    int c = w*8 + i; int r = c*8 + (l>>3);
    int gc = (((l&7) ^ (r&7))<<3);
    gload16(projl + (size_t)r*64 + gc, ps + c*512);
  }
  __syncthreads();
  int rt = w&1, cb = (w>>1)*8;
  f32x4 acc[8] = {};
  #pragma unroll
  for(int kk=0;kk<2;kk++){
    int ar = rt*16 + (l&15);
    int slot = kk*4 + (l>>4);
    short8 a = *(const short8*)(dns + ar*64 + ((slot^(ar&7))<<3));
    #pragma unroll
    for(int ct=0;ct<8;ct++){
      int br = (cb+ct)*16 + (l&15);
      short8 b = *(const short8*)(ps + br*64 + ((slot^(br&7))<<3));
      acc[ct] = __builtin_amdgcn_mfma_f32_16x16x32_bf16(a, b, acc[ct], 0, 0, 0);
    }
  }
  __syncthreads();
  #pragma unroll
  for(int ct=0;ct<8;ct++){
    int col = (cb+ct)*16 + (l&15);
    #pragma unroll
    for(int i=0;i<4;i++){
      int row = rt*16 + (l>>4)*4 + i;
      uni[row*264 + col] = acc[ct][i];
    }
  }
  __syncthreads();
  int r = t>>3, sub = t&7;
  float* rowp = uni + r*264 + sub*32;
  f32x4 v[8];
  #pragma unroll
  for(int jj=0;jj<8;jj++) v[jj] = *(const f32x4*)(rowp + jj*4);
  float m = -3.0e38f;
  #pragma unroll
  for(int jj=0;jj<8;jj++)
    #pragma unroll
    for(int i=0;i<4;i++) m = fmaxf(m, v[jj][i]);
  m = fmaxf(m, __shfl_xor(m,1));
  m = fmaxf(m, __shfl_xor(m,2));
  m = fmaxf(m, __shfl_xor(m,4));
  if(z==0){
    us8 dvu = *(const us8*)(dns + r*64 + ((sub^(r&7))<<3));
    float s2 = 0.f;
    #pragma unroll
    for(int j=0;j<8;j++){ float xx = bf2f(dvu[j]); s2 += xx*xx; }
    s2 += __shfl_xor(s2,1); s2 += __shfl_xor(s2,2); s2 += __shfl_xor(s2,4);
    float ds = 0.5f*s2;
    unsigned short* op = qp + (R0+r)*256 + sub*32;
    #pragma unroll
    for(int jj=0;jj<8;jj++){
      us4 u4;
      #pragma unroll
      for(int i=0;i<4;i++) u4[i] = f2bf(expf(v[jj][i] - ds - m)*0.0625f + 1e-4f);
      *(us4*)(op + jj*4) = u4;
    }
  } else {
    float bm = m;
    bm = fmaxf(bm, __shfl_xor(bm,8));
    bm = fmaxf(bm, __shfl_xor(bm,16));
    bm = fmaxf(bm, __shfl_xor(bm,32));
    __shared__ float wm[4];
    if(l==0) wm[w] = bm;
    __syncthreads();
    if(t==0){
      float g = fmaxf(fmaxf(wm[0],wm[1]),fmaxf(wm[2],wm[3]));
      atomicMax(gmaxbits, enc_max(g));
    }
  }
}

__global__ __launch_bounds__(256) void featB_k(const unsigned short* __restrict__ kn,
    const unsigned short* __restrict__ projl, const unsigned int* __restrict__ gmaxbits,
    unsigned short* __restrict__ kp){
  __shared__ __attribute__((aligned(16))) float uni[32*264];
  __shared__ __attribute__((aligned(16))) unsigned short dns[2048];
  unsigned short* ps = (unsigned short*)uni;
  int t = threadIdx.x;
  int w = t>>6, l = t&63;
  size_t R0 = (size_t)blockIdx.x*32;
  {
    int c = w; int r = c*8 + (l>>3);
    int gc = (((l&7) ^ (r&7))<<3);
    gload16(kn + (R0+r)*64 + gc, dns + c*512);
  }
  #pragma unroll
  for(int i=0;i<8;i++){
    int c = w*8 + i; int r = c*8 + (l>>3);
    int gc = (((l&7) ^ (r&7))<<3);
    gload16(projl + (size_t)r*64 + gc, ps + c*512);
  }
  __syncthreads();
  int rt = w&1, cb = (w>>1)*8;
  f32x4 acc[8] = {};
  #pragma unroll
  for(int kk=0;kk<2;kk++){
    int ar = rt*16 + (l&15);
    int slot = kk*4 + (l>>4);
    short8 a = *(const short8*)(dns + ar*64 + ((slot^(ar&7))<<3));
    #pragma unroll
    for(int ct=0;ct<8;ct++){
      int br = (cb+ct)*16 + (l&15);
      short8 b = *(const short8*)(ps + br*64 + ((slot^(br&7))<<3));
      acc[ct] = __builtin_amdgcn_mfma_f32_16x16x32_bf16(a, b, acc[ct], 0, 0, 0);
    }
  }
  __syncthreads();
  #pragma unroll
  for(int ct=0;ct<8;ct++){
    int col = (cb+ct)*16 + (l&15);
    #pragma unroll
    for(int i=0;i<4;i++){
      int row = rt*16 + (l>>4)*4 + i;
      uni[row*264 + col] = acc[ct][i];
    }
  }
  __syncthreads();
  float g = dec_max(gmaxbits[0]);
  int r = t>>3, sub = t&7;
  us8 dvu = *(const us8*)(dns + r*64 + ((sub^(r&7))<<3));
  float s2 = 0.f;
  #pragma unroll
  for(int j=0;j<8;j++){ float xx = bf2f(dvu[j]); s2 += xx*xx; }
  s2 += __shfl_xor(s2,1); s2 += __shfl_xor(s2,2); s2 += __shfl_xor(s2,4);
  float ds = 0.5f*s2;
  float* rowp = uni + r*264 + sub*32;
  unsigned short* op = kp + (R0+r)*256 + sub*32;
  #pragma unroll
  for(int jj=0;jj<8;jj++){
    f32x4 v = *(const f32x4*)(rowp + jj*4);
    us4 u4;
    #pragma unroll
    for(int i=0;i<4;i++) u4[i] = f2bf(expf(v[i] - ds - g)*0.0625f + 1e-4f);
    *(us4*)(op + jj*4) = u4;
  }
}

// ---------------- quadratic causal attention: per-kt, dbuf, 2 barriers/kt ---
__global__ __launch_bounds__(256) void attn_k(const unsigned short* __restrict__ qp,
    const unsigned short* __restrict__ kp, const unsigned short* __restrict__ vn,
    unsigned short* __restrict__ ob){
  int qt = blockIdx.x, bh = blockIdx.y;
  int b = bh>>3, hh = bh&7;
  __shared__ __attribute__((aligned(16))) unsigned short qs[8192];
  __shared__ __attribute__((aligned(16))) unsigned short ks[2][8192];
  __shared__ __attribute__((aligned(16))) unsigned short VTs[2][2176];  // [d*34+r]
  __shared__ __attribute__((aligned(16))) unsigned short Sb[2][1152];   // [r*36+c]
  __shared__ float dens[2][32];
  int t = threadIdx.x;
  int w = t>>6, l = t&63;
  int qh = w>>1, nc = w&1;
  // stage q tile
  #pragma unroll
  for(int i=0;i<4;i++){
    int c = w*4 + i; int r = (c<<1) + (l>>5); int sl = l&31;
    int gc = ((sl ^ (r&7))<<3);
    int gr = qt*32 + r; if(gr >= SEQL) gr = 0;
    gload16(qp + ((size_t)bh*SEQL + gr)*256 + gc, qs + c*512);
  }
  auto stageK = [&](int kt, int bu){
    #pragma unroll
    for(int i=0;i<4;i++){
      int c = w*4 + i; int r = (c<<1) + (l>>5); int sl = l&31;
      int gc = ((sl ^ (r&7))<<3);
      int gk = kt*32 + r; if(gk >= SEQL) gk = 0;
      gload16(kp + ((size_t)bh*SEQL + gk)*256 + gc, ks[bu] + c*512);
    }
    int rr = t>>3, od = (t&7)*8;
    int gk = kt*32 + rr;
    us8 uv = {};
    if(gk < SEQL) uv = *(const us8*)(vn + ((size_t)bh*SEQL + gk)*64 + od);
    #pragma unroll
    for(int j=0;j<8;j++) VTs[bu][(od+j)*34 + rr] = uv[j];
  };
  stageK(0, 0);
  float dreg[4] = {0.f,0.f,0.f,0.f};
  f32x4 oacc[2] = {};
  for(int kt=0; kt<=qt; kt++){
    int cur = kt&1;
    __syncthreads();            // stage[cur] done; prev PV done
    if(kt < qt) stageK(kt+1, cur^1);
    // score phase on ks[cur]
    f32x4 sacc = {};
    #pragma unroll
    for(int kk=0;kk<8;kk++){
      int ar = qh*16 + (l&15); int slot = kk*4 + (l>>4);
      short8 a = *(const short8*)(qs + ar*256 + ((slot^(ar&7))<<3));
      int br = nc*16 + (l&15);
      short8 bb2 = *(const short8*)(ks[cur] + br*256 + ((slot^(br&7))<<3));
      sacc = __builtin_amdgcn_mfma_f32_16x16x32_bf16(a, bb2, sacc, 0, 0, 0);
    }
    int scol = nc*16 + (l&15);
    int gcol = kt*32 + scol;
    float dp[4];
    #pragma unroll
    for(int i=0;i<4;i++){
      int sr = qh*16 + (l>>4)*4 + i;
      int grw = qt*32 + sr;
      float v2 = sacc[i];
      if(gcol > grw) v2 = 0.f;
      Sb[cur][sr*36 + scol] = f2bf(v2);
      dp[i] = v2;
    }
    #pragma unroll
    for(int off=1;off<16;off<<=1)
      #pragma unroll
      for(int i=0;i<4;i++) dp[i] += __shfl_xor(dp[i], off);
    #pragma unroll
    for(int i=0;i<4;i++) dreg[i] += dp[i];
    __syncthreads();            // Sb[cur] ready (also drains stage(kt+1))
    // PV phase on Sb[cur], VTs[cur]
    short8 a2 = *(const short8*)(Sb[cur] + (qh*16 + (l&15))*36 + (l>>4)*8);
    #pragma unroll
    for(int n2=0;n2<2;n2++){
      int d = nc*32 + n2*16 + (l&15);
      short8 b2 = *(const short8*)(VTs[cur] + d*34 + (l>>4)*8);
      oacc[n2] = __builtin_amdgcn_mfma_f32_16x16x32_bf16(a2, b2, oacc[n2], 0, 0, 0);
    }
  }
  if((l&15)==0){
    #pragma unroll
    for(int i=0;i<4;i++) dens[nc][qh*16 + (l>>4)*4 + i] = dreg[i];
  }
  __syncthreads();
  #pragma unroll
  for(int n2=0;n2<2;n2++){
    int d = nc*32 + n2*16 + (l&15);
    #pragma unroll
    for(int i=0;i<4;i++){
      int rit = qh*16 + (l>>4)*4 + i;
      int gr = qt*32 + rit;
      if(gr < SEQL){
        float inv = 1.f/(dens[0][rit] + dens[1][rit]);
        ob[((size_t)(b*SEQL+gr))*DIMM + hh*64 + d] = f2bf(oacc[n2][i]*inv);
      }
    }
  }
}

// ---------------- loss ------------------------------------------------------
__global__ __launch_bounds__(256) void loss_k(const float* __restrict__ logits,
    const int* __restrict__ iarr, const int* __restrict__ inds,
    float* __restrict__ rnll){
  int row = blockIdx.x; int t = threadIdx.x;
  const float* lr = logits + (size_t)row*VSZ;
  float m = -3.0e38f;
  for(int j=t;j<VSZ;j+=256) m = fmaxf(m, lr[j]);
  m = blk_max(m);
  float s = 0.f;
  for(int j=t;j<VSZ;j+=256) s += expf(lr[j]-m);
  s = blk_sum(s);
  if(t==0){
    int b = row/SEQL, l = row - b*SEQL;
    int tgt = tok_at(iarr, inds, b, l+1);
    rnll[row] = (m + logf(s)) - lr[tgt];
  }
}

__global__ __launch_bounds__(256) void fin_k(const float* __restrict__ rnll,
    float* __restrict__ out){
  int t = threadIdx.x;
  float s = 0.f;
  for(int i=t;i<NROWS;i+=256) s += rnll[i];
  s = blk_sum(s);
  if(t==0) out[0] = s/(float)NROWS;
}

// ---------------------------------------------------------------------------
extern "C" void kernel_launch(void* const* d_in, const int* in_sizes, int n_in,
                              void* d_out, int out_size, void* d_ws, size_t ws_size,
                              hipStream_t stream){
  (void)in_sizes; (void)n_in; (void)out_size; (void)ws_size;
  const float* x        = (const float*)d_in[0];
  const float* xn       = (const float*)d_in[1];
  const int*   iarr     = (const int*)  d_in[2];
  const float* conv1_w  = (const float*)d_in[3];
  const float* conv1_b  = (const float*)d_in[4];
  const float* conv2_w  = (const float*)d_in[5];
  const float* conv2_b  = (const float*)d_in[6];
  const float* codebook = (const float*)d_in[7];
  const float* proj     = (const float*)d_in[8];
  const float* tok_emb  = (const float*)d_in[9];
  const float* pos_emb  = (const float*)d_in[10];
  const float* ln1_g    = (const float*)d_in[11];
  const float* ln1_b    = (const float*)d_in[12];
  const float* wq       = (const float*)d_in[13];
  const float* wk       = (const float*)d_in[14];
  const float* wv       = (const float*)d_in[15];
  const float* wo       = (const float*)d_in[16];
  const float* bo       = (const float*)d_in[17];
  const float* ln2_g    = (const float*)d_in[18];
  const float* ln2_b    = (const float*)d_in[19];
  const float* ff1_w    = (const float*)d_in[20];
  const float* ff1_b    = (const float*)d_in[21];
  const float* ff2_w    = (const float*)d_in[22];
  const float* ff2_b    = (const float*)d_in[23];
  const float* lnf_g    = (const float*)d_in[24];
  const float* lnf_b    = (const float*)d_in[25];
  const float* logits_w = (const float*)d_in[26];
  const float* logits_b = (const float*)d_in[27];

  float* wsf = (float*)d_ws;
  size_t off = 0;
  unsigned short* qp_bf = (unsigned short*)(wsf + off); off += 2129920;
  unsigned short* kp_bf = (unsigned short*)(wsf + off); off += 2129920;
  float* h = wsf + off; off += 1064960;
  unsigned short* x1b = (unsigned short*)(wsf + off); off += 532480;
  unsigned short* qkvb = (unsigned short*)(wsf + off); off += 1597440;
  unsigned short* ob  = (unsigned short*)(wsf + off); off += 532480;
  unsigned short* projb = (unsigned short*)(wsf + off); off += 49152;
  unsigned short* wall  = (unsigned short*)(wsf + off); off += 9437184; // 6 layers
  unsigned short* logt  = (unsigned short*)(wsf + off); off += 133888;
  unsigned short* ffmid = (unsigned short*)(wsf + off); off += 2129920;
  float* logits = wsf + off; off += 1087840;
  int* inds = (int*)(wsf + off); off += 2048;
  unsigned int* gmaxbits = (unsigned int*)(wsf + off); off += 64;
  float* rnll = wsf + off; off += 2112;

  // pre-loop aliases into regions that are dead before the layer loop
  float* c1 = logits;                                  // 524288 f32
  unsigned short* icol = ffmid;                        // 2048*2048 us
  float* zbuf = (float*)qp_bf;                         // 2048*64 f32
  unsigned short* cw2b = (unsigned short*)kp_bf;       // 64*2048 us

  unsigned short* qnb = qkvb;
  unsigned short* knb = qkvb + QSEG;
  unsigned short* vnb = qkvb + 2*QSEG;

  prep_k<<<18816,256,0,stream>>>(wq, wk, wv, wo, ff1_w, ff2_w, wall,
      conv2_w, cw2b, proj, projb, logits_w, logt, gmaxbits);
  conv1_k<<<2048,256,0,stream>>>(x, xn, conv1_w, conv1_b, c1);
  im2col_k<<<2048,256,0,stream>>>(c1, icol);
  mgemm32_k<0><<<dim3(1,64),256,0,stream>>>(icol, cw2b, conv2_b, zbuf, 64, 2048);
  vq_k<<<2048,256,0,stream>>>(zbuf, codebook, inds);
  embed_k<<<(NROWS*DIMM)/256,256,0,stream>>>(iarr, inds, tok_emb, pos_emb, h);

  for(int l=0;l<6;l++){
    unsigned short* wl    = wall + (size_t)l*WLAYER;
    unsigned short* wqkvt = wl;
    unsigned short* wot   = wl + 786432;
    unsigned short* ff1t  = wl + 1048576;
    unsigned short* ff2t  = wl + 2097152;
    ln_k<<<520,256,0,stream>>>(h, ln1_g+l*DIMM, ln1_b+l*DIMM, x1b);
    gemm64x128_k<1><<<dim3(12,33),256,0,stream>>>(x1b, wqkvt, nullptr, qkvb, NROWS, 1536, DIMM);
    featA_k<<<dim3(520,2),256,0,stream>>>(qnb, knb, projb + l*16384, qp_bf, gmaxbits + l);
    featB_k<<<520,256,0,stream>>>(knb, projb + l*16384, gmaxbits + l, kp_bf);
    attn_k<<<dim3(5,NBH),256,0,stream>>>(qp_bf, kp_bf, vnb, ob);
    mgemm32_k<1><<<dim3(8,65),256,0,stream>>>(ob, wot, bo+l*DIMM, h, DIMM, DIMM);
    ln_k<<<520,256,0,stream>>>(h, ln2_g+l*DIMM, ln2_b+l*DIMM, x1b);
    gemm64x128_k<4><<<dim3(16,33),256,0,stream>>>(x1b, ff1t, ff1_b+l*2048, ffmid, NROWS, 2048, DIMM);
    mgemm32_k<1><<<dim3(8,65),256,0,stream>>>(ffmid, ff2t, ff2_b+l*DIMM, h, DIMM, 2048);
  }

  ln_k<<<520,256,0,stream>>>(h, lnf_g, lnf_b, x1b);
  mgemm_k<<<dim3(9,33),256,0,stream>>>(x1b, logt, logits_b, logits, NROWS, VSZ, DIMM);
  loss_k<<<NROWS,256,0,stream>>>(logits, iarr, inds, rnll);
  fin_k<<<1,256,0,stream>>>(rnll, (float*)d_out);
}